// Round 1
// baseline (632.634 us; speedup 1.0000x reference)
//
#include <hip/hip_runtime.h>

// EntityLinker fused edge-MLP for MI355X (gfx950).
// Round 1: correctness-first bf16 MFMA implementation.
//   prep_w1/prep_w2: cast+transpose weights to bf16 [n][k] in d_ws.
//   fused_mlp: per 64-edge tile -- gather+build EI in LDS, 3-layer MLP fused,
//              layers 1-2 via mfma_f32_16x16x32_bf16, layer 3 (N=2) via VALU.

#define H 128

typedef __bf16 bf16x8 __attribute__((ext_vector_type(8)));
typedef float f32x4 __attribute__((ext_vector_type(4)));

__device__ __forceinline__ unsigned short f2bf(float f) {
    unsigned u = __builtin_bit_cast(unsigned, f);
    u += 0x7FFFu + ((u >> 16) & 1u);   // RNE
    return (unsigned short)(u >> 16);
}
__device__ __forceinline__ float bf2f(unsigned short h) {
    unsigned u = ((unsigned)h) << 16;
    return __builtin_bit_cast(float, u);
}

__global__ void prep_w1(const float* __restrict__ W1, unsigned short* __restrict__ W1T) {
    int idx = blockIdx.x * 256 + threadIdx.x;      // 131072 total
    int n = idx >> 9;                              // 0..255
    int k = idx & 511;                             // 0..511
    W1T[idx] = f2bf(W1[k * 256 + n]);              // W1 is [512][256] row-major (in,out)
}

__global__ void prep_w2(const float* __restrict__ W2, unsigned short* __restrict__ W2T) {
    int idx = blockIdx.x * 256 + threadIdx.x;      // 32768 total
    int n = idx >> 8;                              // 0..127
    int k = idx & 255;                             // 0..255
    W2T[idx] = f2bf(W2[k * 128 + n]);              // W2 is [256][128]
}

__launch_bounds__(256)
__global__ void fused_mlp(const float* __restrict__ node,
                          const int* __restrict__ src,
                          const int* __restrict__ dst,
                          const unsigned short* __restrict__ W1T,  // [256][512] bf16
                          const float* __restrict__ b1,
                          const unsigned short* __restrict__ W2T,  // [128][256] bf16
                          const float* __restrict__ b2,
                          const float* __restrict__ W3,            // [128][2] f32
                          const float* __restrict__ b3,
                          float* __restrict__ out,                 // [E][2] f32
                          int E) {
    // EI region: [64][520] bf16 (pad 512->520: row stride 1040B = 4 banks/row, 16B aligned).
    // Overlays after layer 1: x1 [64][264] at offset 0; x2 [64][136] at offset 64*264.
    __shared__ __align__(16) unsigned short sEI[64 * 520];   // 66560 B
    __shared__ __align__(16) unsigned short sW[256 * 40];    // 20480 B (weight K-chunk, pad 32->40)
    __shared__ float sW3[256];                               // layer-3 weights f32

    const int t = threadIdx.x;
    const int e0 = blockIdx.x * 64;

    // ---------------- Phase A: gather + build edge-input tile ----------------
    {
        int r = t >> 2;            // edge row 0..63
        int p = t & 3;             // 32-col quarter
        int e = e0 + r;
        int ec = e < E ? e : (E - 1);
        const float* hi = node + (long)src[ec] * H + p * 32;
        const float* hj = node + (long)dst[ec] * H + p * 32;
        unsigned short* row = sEI + r * 520;
#pragma unroll
        for (int b = 0; b < 8; b++) {
            float4 a = ((const float4*)hi)[b];
            float4 c = ((const float4*)hj)[b];
            int c0 = p * 32 + b * 4;
            ushort4 wa, wc, wd, wp;
            wa.x = f2bf(a.x); wa.y = f2bf(a.y); wa.z = f2bf(a.z); wa.w = f2bf(a.w);
            wc.x = f2bf(c.x); wc.y = f2bf(c.y); wc.z = f2bf(c.z); wc.w = f2bf(c.w);
            wd.x = f2bf(fabsf(a.x - c.x)); wd.y = f2bf(fabsf(a.y - c.y));
            wd.z = f2bf(fabsf(a.z - c.z)); wd.w = f2bf(fabsf(a.w - c.w));
            wp.x = f2bf(a.x * c.x); wp.y = f2bf(a.y * c.y);
            wp.z = f2bf(a.z * c.z); wp.w = f2bf(a.w * c.w);
            *(ushort4*)(row + c0)       = wa;
            *(ushort4*)(row + 128 + c0) = wc;
            *(ushort4*)(row + 256 + c0) = wd;
            *(ushort4*)(row + 384 + c0) = wp;
        }
        sW3[t] = W3[t];            // 256 elements == 128*2, exactly one per thread
    }

    const int lane = t & 63;
    const int wv = t >> 6;         // wave 0..3
    const int quad = lane >> 4;
    const int lrow = lane & 15;

    // ---------------- Phase B: layer 1  (M=64, N=256, K=512) ----------------
    f32x4 acc[4][4];
#pragma unroll
    for (int mt = 0; mt < 4; mt++)
#pragma unroll
        for (int nt = 0; nt < 4; nt++)
            acc[mt][nt] = (f32x4){0.f, 0.f, 0.f, 0.f};

    const int nb = wv * 64;        // wave's 64-column slice of N=256
    int aoff[4], boff[4];
#pragma unroll
    for (int mt = 0; mt < 4; mt++) aoff[mt] = (mt * 16 + lrow) * 520 + quad * 8;
#pragma unroll
    for (int nt = 0; nt < 4; nt++) boff[nt] = (nb + nt * 16 + lrow) * 40 + quad * 8;

    for (int ks = 0; ks < 16; ks++) {
        const int k0 = ks * 32;
        __syncthreads();           // ks=0: EI visible; ks>0: prior chunk's B-reads done
        // stage W1T[:, k0:k0+32] -> sW [256][40]
#pragma unroll
        for (int j = 0; j < 4; j++) {
            int u = j * 256 + t;
            int n = u >> 2, part = u & 3;
            uint4 v = *(const uint4*)(W1T + n * 512 + k0 + part * 8);
            *(uint4*)(sW + n * 40 + part * 8) = v;
        }
        __syncthreads();
        bf16x8 av[4], bv[4];
#pragma unroll
        for (int mt = 0; mt < 4; mt++) av[mt] = *(const bf16x8*)(sEI + aoff[mt] + k0);
#pragma unroll
        for (int nt = 0; nt < 4; nt++) bv[nt] = *(const bf16x8*)(sW + boff[nt]);
#pragma unroll
        for (int mt = 0; mt < 4; mt++)
#pragma unroll
            for (int nt = 0; nt < 4; nt++)
                acc[mt][nt] = __builtin_amdgcn_mfma_f32_16x16x32_bf16(av[mt], bv[nt], acc[mt][nt], 0, 0, 0);
    }

    // ---------------- Phase C: relu+bias -> x1 bf16 in LDS (overlay EI) ----------------
    float b1v[4];
#pragma unroll
    for (int nt = 0; nt < 4; nt++) b1v[nt] = b1[nb + nt * 16 + lrow];

    __syncthreads();               // all waves done reading sEI / sW for layer 1
    unsigned short* sx1 = sEI;     // [64][264]
#pragma unroll
    for (int mt = 0; mt < 4; mt++)
#pragma unroll
        for (int nt = 0; nt < 4; nt++)
#pragma unroll
            for (int i = 0; i < 4; i++) {
                int row = mt * 16 + quad * 4 + i;    // C/D: row = quad*4 + reg
                int col = nb + nt * 16 + lrow;       //      col = lane&15
                float v = acc[mt][nt][i] + b1v[nt];
                v = v > 0.f ? v : 0.f;
                sx1[row * 264 + col] = f2bf(v);
            }

    // ---------------- Phase D: layer 2  (M=64, N=128, K=256) ----------------
    f32x4 acc2[4][2];
#pragma unroll
    for (int mt = 0; mt < 4; mt++)
#pragma unroll
        for (int nt = 0; nt < 2; nt++)
            acc2[mt][nt] = (f32x4){0.f, 0.f, 0.f, 0.f};

    const int nb2 = wv * 32;       // wave's 32-column slice of N=128
    int aoff2[4], boff2[2];
#pragma unroll
    for (int mt = 0; mt < 4; mt++) aoff2[mt] = (mt * 16 + lrow) * 264 + quad * 8;
#pragma unroll
    for (int nt = 0; nt < 2; nt++) boff2[nt] = (nb2 + nt * 16 + lrow) * 40 + quad * 8;

    for (int ks = 0; ks < 8; ks++) {
        const int k0 = ks * 32;
        __syncthreads();           // x1 writes visible (ks=0) / prior chunk reads done
#pragma unroll
        for (int j = 0; j < 2; j++) {
            int u = j * 256 + t;
            int n = u >> 2, part = u & 3;
            uint4 v = *(const uint4*)(W2T + n * 256 + k0 + part * 8);
            *(uint4*)(sW + n * 40 + part * 8) = v;
        }
        __syncthreads();
        bf16x8 av2[4], bv2[2];
#pragma unroll
        for (int mt = 0; mt < 4; mt++) av2[mt] = *(const bf16x8*)(sx1 + aoff2[mt] + k0);
#pragma unroll
        for (int nt = 0; nt < 2; nt++) bv2[nt] = *(const bf16x8*)(sW + boff2[nt]);
#pragma unroll
        for (int mt = 0; mt < 4; mt++)
#pragma unroll
            for (int nt = 0; nt < 2; nt++)
                acc2[mt][nt] = __builtin_amdgcn_mfma_f32_16x16x32_bf16(av2[mt], bv2[nt], acc2[mt][nt], 0, 0, 0);
    }

    // ---------------- Phase E: relu+bias -> x2 bf16 in LDS ----------------
    unsigned short* sx2 = sEI + 64 * 264;   // [64][136], disjoint from x1 region
    float b2v[2];
#pragma unroll
    for (int nt = 0; nt < 2; nt++) b2v[nt] = b2[nb2 + nt * 16 + lrow];
#pragma unroll
    for (int mt = 0; mt < 4; mt++)
#pragma unroll
        for (int nt = 0; nt < 2; nt++)
#pragma unroll
            for (int i = 0; i < 4; i++) {
                int row = mt * 16 + quad * 4 + i;
                int col = nb2 + nt * 16 + lrow;
                float v = acc2[mt][nt][i] + b2v[nt];
                v = v > 0.f ? v : 0.f;
                sx2[row * 136 + col] = f2bf(v);
            }
    __syncthreads();

    // ---------------- Phase F: layer 3 (N=2) via VALU ----------------
    if (t < 128) {
        int r = t >> 1, c = t & 1;
        const unsigned short* xr = sx2 + r * 136;
        float s = 0.f;
#pragma unroll 8
        for (int k = 0; k < 128; k++)
            s += bf2f(xr[k]) * sW3[k * 2 + c];
        int e = e0 + r;
        if (e < E) out[e * 2 + c] = s + b3[c];
    }
}

extern "C" void kernel_launch(void* const* d_in, const int* in_sizes, int n_in,
                              void* d_out, int out_size, void* d_ws, size_t ws_size,
                              hipStream_t stream) {
    const float* node = (const float*)d_in[0];
    const int* src    = (const int*)d_in[1];
    const int* dst    = (const int*)d_in[2];
    const float* W1   = (const float*)d_in[3];
    const float* b1   = (const float*)d_in[4];
    const float* W2   = (const float*)d_in[5];
    const float* b2   = (const float*)d_in[6];
    const float* W3   = (const float*)d_in[7];
    const float* b3   = (const float*)d_in[8];
    float* out = (float*)d_out;
    const int E = in_sizes[1];

    unsigned short* W1T = (unsigned short*)d_ws;       // [256][512] bf16 = 256 KiB
    unsigned short* W2T = W1T + 512 * 256;             // [128][256] bf16 = 64 KiB

    hipLaunchKernelGGL(prep_w1, dim3(512), dim3(256), 0, stream, W1, W1T);
    hipLaunchKernelGGL(prep_w2, dim3(128), dim3(256), 0, stream, W2, W2T);
    const int nblk = (E + 63) / 64;
    hipLaunchKernelGGL(fused_mlp, dim3(nblk), dim3(256), 0, stream,
                       node, src, dst, W1T, b1, W2T, b2, W3, b3, out, E);
}

// Round 2
// 474.060 us; speedup vs baseline: 1.3345x; 1.3345x over previous
//
#include <hip/hip_runtime.h>

// EntityLinker fused edge-MLP for MI355X (gfx950).
// Round 2: occupancy + barrier elimination.
//   - B-operands (W1T/W2T bf16) loaded straight from global (L2-resident,
//     320 KB total) into registers -> no sW LDS, no per-K-chunk barriers.
//   - LDS = 67.6 KB -> 2 WG/CU (was 88 KB -> 1 WG/CU).

#define H 128

typedef __bf16 bf16x8 __attribute__((ext_vector_type(8)));
typedef float f32x4 __attribute__((ext_vector_type(4)));

__device__ __forceinline__ unsigned short f2bf(float f) {
    unsigned u = __builtin_bit_cast(unsigned, f);
    u += 0x7FFFu + ((u >> 16) & 1u);   // RNE
    return (unsigned short)(u >> 16);
}
__device__ __forceinline__ float bf2f(unsigned short h) {
    unsigned u = ((unsigned)h) << 16;
    return __builtin_bit_cast(float, u);
}

__global__ void prep_w1(const float* __restrict__ W1, unsigned short* __restrict__ W1T) {
    int idx = blockIdx.x * 256 + threadIdx.x;      // 131072 total
    int n = idx >> 9;                              // 0..255
    int k = idx & 511;                             // 0..511
    W1T[idx] = f2bf(W1[k * 256 + n]);              // W1 is [512][256] row-major (in,out)
}

__global__ void prep_w2(const float* __restrict__ W2, unsigned short* __restrict__ W2T) {
    int idx = blockIdx.x * 256 + threadIdx.x;      // 32768 total
    int n = idx >> 8;                              // 0..127
    int k = idx & 255;                             // 0..255
    W2T[idx] = f2bf(W2[k * 128 + n]);              // W2 is [256][128]
}

__launch_bounds__(256, 2)
__global__ void fused_mlp(const float* __restrict__ node,
                          const int* __restrict__ src,
                          const int* __restrict__ dst,
                          const unsigned short* __restrict__ W1T,  // [256][512] bf16
                          const float* __restrict__ b1,
                          const unsigned short* __restrict__ W2T,  // [128][256] bf16
                          const float* __restrict__ b2,
                          const float* __restrict__ W3,            // [128][2] f32
                          const float* __restrict__ b3,
                          float* __restrict__ out,                 // [E][2] f32
                          int E) {
    // EI region: [64][520] bf16 (row stride 1040B, 16B aligned).
    // Overlays after layer 1: x1 [64][264] at offset 0; x2 [64][136] after it.
    __shared__ __align__(16) unsigned short sEI[64 * 520];   // 66560 B
    __shared__ float sW3[256];                               // layer-3 weights f32
    // total ~67.6 KB -> 2 workgroups/CU

    const int t = threadIdx.x;
    const int e0 = blockIdx.x * 64;

    // ---------------- Phase A: gather + build edge-input tile ----------------
    {
        int r = t >> 2;            // edge row 0..63
        int p = t & 3;             // 32-col quarter
        int e = e0 + r;
        int ec = e < E ? e : (E - 1);
        const float* hi = node + (long)src[ec] * H + p * 32;
        const float* hj = node + (long)dst[ec] * H + p * 32;
        unsigned short* row = sEI + r * 520;
#pragma unroll
        for (int b = 0; b < 8; b++) {
            float4 a = ((const float4*)hi)[b];
            float4 c = ((const float4*)hj)[b];
            int c0 = p * 32 + b * 4;
            ushort4 wa, wc, wd, wp;
            wa.x = f2bf(a.x); wa.y = f2bf(a.y); wa.z = f2bf(a.z); wa.w = f2bf(a.w);
            wc.x = f2bf(c.x); wc.y = f2bf(c.y); wc.z = f2bf(c.z); wc.w = f2bf(c.w);
            wd.x = f2bf(fabsf(a.x - c.x)); wd.y = f2bf(fabsf(a.y - c.y));
            wd.z = f2bf(fabsf(a.z - c.z)); wd.w = f2bf(fabsf(a.w - c.w));
            wp.x = f2bf(a.x * c.x); wp.y = f2bf(a.y * c.y);
            wp.z = f2bf(a.z * c.z); wp.w = f2bf(a.w * c.w);
            *(ushort4*)(row + c0)       = wa;
            *(ushort4*)(row + 128 + c0) = wc;
            *(ushort4*)(row + 256 + c0) = wd;
            *(ushort4*)(row + 384 + c0) = wp;
        }
        sW3[t] = W3[t];            // 256 elements == 128*2, one per thread
    }

    const int lane = t & 63;
    const int wv = t >> 6;         // wave 0..3
    const int quad = lane >> 4;
    const int lrow = lane & 15;

    // ---------------- Phase B: layer 1  (M=64, N=256, K=512) ----------------
    f32x4 acc[4][4];
#pragma unroll
    for (int mt = 0; mt < 4; mt++)
#pragma unroll
        for (int nt = 0; nt < 4; nt++)
            acc[mt][nt] = (f32x4){0.f, 0.f, 0.f, 0.f};

    const int nb = wv * 64;        // wave's 64-column slice of N=256
    const unsigned short* sA[4];
    const unsigned short* w1p[4];
#pragma unroll
    for (int mt = 0; mt < 4; mt++) sA[mt] = sEI + (mt * 16 + lrow) * 520 + quad * 8;
#pragma unroll
    for (int nt = 0; nt < 4; nt++) w1p[nt] = W1T + (nb + nt * 16 + lrow) * 512 + quad * 8;

    __syncthreads();               // EI tile visible to all waves

#pragma unroll
    for (int ks = 0; ks < 16; ks++) {
        const int k0 = ks * 32;
        bf16x8 av[4], bv[4];
#pragma unroll
        for (int nt = 0; nt < 4; nt++) bv[nt] = *(const bf16x8*)(w1p[nt] + k0);  // L2-hot
#pragma unroll
        for (int mt = 0; mt < 4; mt++) av[mt] = *(const bf16x8*)(sA[mt] + k0);
#pragma unroll
        for (int mt = 0; mt < 4; mt++)
#pragma unroll
            for (int nt = 0; nt < 4; nt++)
                acc[mt][nt] = __builtin_amdgcn_mfma_f32_16x16x32_bf16(av[mt], bv[nt], acc[mt][nt], 0, 0, 0);
    }

    // ---------------- Phase C: relu+bias -> x1 bf16 in LDS (overlay EI) ----------------
    float b1v[4];
#pragma unroll
    for (int nt = 0; nt < 4; nt++) b1v[nt] = b1[nb + nt * 16 + lrow];

    __syncthreads();               // all waves done reading sEI for layer 1
    unsigned short* sx1 = sEI;     // [64][264]
#pragma unroll
    for (int mt = 0; mt < 4; mt++)
#pragma unroll
        for (int nt = 0; nt < 4; nt++)
#pragma unroll
            for (int i = 0; i < 4; i++) {
                int row = mt * 16 + quad * 4 + i;    // C/D: row = quad*4 + reg
                int col = nb + nt * 16 + lrow;       //      col = lane&15
                float v = acc[mt][nt][i] + b1v[nt];
                v = v > 0.f ? v : 0.f;
                sx1[row * 264 + col] = f2bf(v);
            }
    __syncthreads();               // x1 complete before layer-2 reads

    // ---------------- Phase D: layer 2  (M=64, N=128, K=256) ----------------
    f32x4 acc2[4][2];
#pragma unroll
    for (int mt = 0; mt < 4; mt++)
#pragma unroll
        for (int nt = 0; nt < 2; nt++)
            acc2[mt][nt] = (f32x4){0.f, 0.f, 0.f, 0.f};

    const int nb2 = wv * 32;       // wave's 32-column slice of N=128
    const unsigned short* sA2[4];
    const unsigned short* w2p[2];
#pragma unroll
    for (int mt = 0; mt < 4; mt++) sA2[mt] = sx1 + (mt * 16 + lrow) * 264 + quad * 8;
#pragma unroll
    for (int nt = 0; nt < 2; nt++) w2p[nt] = W2T + (nb2 + nt * 16 + lrow) * 256 + quad * 8;

#pragma unroll
    for (int ks = 0; ks < 8; ks++) {
        const int k0 = ks * 32;
        bf16x8 av2[4], bv2[2];
#pragma unroll
        for (int nt = 0; nt < 2; nt++) bv2[nt] = *(const bf16x8*)(w2p[nt] + k0);
#pragma unroll
        for (int mt = 0; mt < 4; mt++) av2[mt] = *(const bf16x8*)(sA2[mt] + k0);
#pragma unroll
        for (int mt = 0; mt < 4; mt++)
#pragma unroll
            for (int nt = 0; nt < 2; nt++)
                acc2[mt][nt] = __builtin_amdgcn_mfma_f32_16x16x32_bf16(av2[mt], bv2[nt], acc2[mt][nt], 0, 0, 0);
    }

    // ---------------- Phase E: relu+bias -> x2 bf16 in LDS ----------------
    unsigned short* sx2 = sEI + 64 * 264;   // [64][136], disjoint from x1 region
    float b2v[2];
#pragma unroll
    for (int nt = 0; nt < 2; nt++) b2v[nt] = b2[nb2 + nt * 16 + lrow];
    __syncthreads();               // layer-2 A-reads of sx1 done everywhere
#pragma unroll
    for (int mt = 0; mt < 4; mt++)
#pragma unroll
        for (int nt = 0; nt < 2; nt++)
#pragma unroll
            for (int i = 0; i < 4; i++) {
                int row = mt * 16 + quad * 4 + i;
                int col = nb2 + nt * 16 + lrow;
                float v = acc2[mt][nt][i] + b2v[nt];
                v = v > 0.f ? v : 0.f;
                sx2[row * 136 + col] = f2bf(v);
            }
    __syncthreads();

    // ---------------- Phase F: layer 3 (N=2) via VALU ----------------
    if (t < 128) {
        int r = t >> 1, c = t & 1;
        const unsigned short* xr = sx2 + r * 136;
        float s = 0.f;
#pragma unroll 8
        for (int k = 0; k < 128; k++)
            s += bf2f(xr[k]) * sW3[k * 2 + c];
        int e = e0 + r;
        if (e < E) out[e * 2 + c] = s + b3[c];
    }
}

extern "C" void kernel_launch(void* const* d_in, const int* in_sizes, int n_in,
                              void* d_out, int out_size, void* d_ws, size_t ws_size,
                              hipStream_t stream) {
    const float* node = (const float*)d_in[0];
    const int* src    = (const int*)d_in[1];
    const int* dst    = (const int*)d_in[2];
    const float* W1   = (const float*)d_in[3];
    const float* b1   = (const float*)d_in[4];
    const float* W2   = (const float*)d_in[5];
    const float* b2   = (const float*)d_in[6];
    const float* W3   = (const float*)d_in[7];
    const float* b3   = (const float*)d_in[8];
    float* out = (float*)d_out;
    const int E = in_sizes[1];

    unsigned short* W1T = (unsigned short*)d_ws;       // [256][512] bf16 = 256 KiB
    unsigned short* W2T = W1T + 512 * 256;             // [128][256] bf16 = 64 KiB

    hipLaunchKernelGGL(prep_w1, dim3(512), dim3(256), 0, stream, W1, W1T);
    hipLaunchKernelGGL(prep_w2, dim3(128), dim3(256), 0, stream, W2, W2T);
    const int nblk = (E + 63) / 64;
    hipLaunchKernelGGL(fused_mlp, dim3(nblk), dim3(256), 0, stream,
                       node, src, dst, W1T, b1, W2T, b2, W3, b3, out, E);
}

// Round 3
// 442.387 us; speedup vs baseline: 1.4300x; 1.0716x over previous
//
#include <hip/hip_runtime.h>

// EntityLinker fused edge-MLP for MI355X (gfx950).
// Round 3: deep register prefetch pipelines to hide L2 latency of weight loads.
//   - Layer-1/2 K-loops: depth-4 B-frag prefetch (global/L2) + depth-2 A-frag
//     prefetch (LDS); prologues hoisted before barriers/epilogues.
//   - Phase F: all-thread half-dots + shfl_xor combine, vectorized LDS reads.
//   - LDS 67.6 KB -> 2 WG/CU; __launch_bounds__(256,2) lets VGPRs grow to ~200.

#define H 128

typedef __bf16 bf16x8 __attribute__((ext_vector_type(8)));
typedef float f32x4 __attribute__((ext_vector_type(4)));

__device__ __forceinline__ unsigned short f2bf(float f) {
    unsigned u = __builtin_bit_cast(unsigned, f);
    u += 0x7FFFu + ((u >> 16) & 1u);   // RNE
    return (unsigned short)(u >> 16);
}
__device__ __forceinline__ float bfhi(unsigned u) {        // high 16 bits as bf16->f32
    return __builtin_bit_cast(float, u & 0xffff0000u);
}
__device__ __forceinline__ float bflo(unsigned u) {        // low 16 bits as bf16->f32
    return __builtin_bit_cast(float, u << 16);
}

__global__ void prep_w1(const float* __restrict__ W1, unsigned short* __restrict__ W1T) {
    int idx = blockIdx.x * 256 + threadIdx.x;      // 131072 total
    int n = idx >> 9;
    int k = idx & 511;
    W1T[idx] = f2bf(W1[k * 256 + n]);              // W1 is [512][256] (in,out)
}

__global__ void prep_w2(const float* __restrict__ W2, unsigned short* __restrict__ W2T) {
    int idx = blockIdx.x * 256 + threadIdx.x;      // 32768 total
    int n = idx >> 8;
    int k = idx & 255;
    W2T[idx] = f2bf(W2[k * 128 + n]);              // W2 is [256][128]
}

__launch_bounds__(256, 2)
__global__ void fused_mlp(const float* __restrict__ node,
                          const int* __restrict__ src,
                          const int* __restrict__ dst,
                          const unsigned short* __restrict__ W1T,  // [256][512] bf16
                          const float* __restrict__ b1,
                          const unsigned short* __restrict__ W2T,  // [128][256] bf16
                          const float* __restrict__ b2,
                          const float* __restrict__ W3,            // [128][2] f32
                          const float* __restrict__ b3,
                          float* __restrict__ out,                 // [E][2] f32
                          int E) {
    __shared__ __align__(16) unsigned short sEI[64 * 520];   // 66560 B; x1/x2 overlay
    __shared__ __align__(16) float sW3[256];                 // de-interleaved: [c][128]

    const int t = threadIdx.x;
    const int e0 = blockIdx.x * 64;

    const int lane = t & 63;
    const int wv = t >> 6;
    const int quad = lane >> 4;
    const int lrow = lane & 15;
    const int nb = wv * 64;        // layer-1 N-slice
    const int nb2 = wv * 32;       // layer-2 N-slice

    const unsigned short* w1p[4];
#pragma unroll
    for (int nt = 0; nt < 4; nt++) w1p[nt] = W1T + (nb + nt * 16 + lrow) * 512 + quad * 8;
    const unsigned short* w2p[2];
#pragma unroll
    for (int nt = 0; nt < 2; nt++) w2p[nt] = W2T + (nb2 + nt * 16 + lrow) * 256 + quad * 8;

    // ---------------- Phase A: gather + build edge-input tile ----------------
    {
        int r = t >> 2;            // edge row 0..63
        int p = t & 3;             // 32-col quarter
        int e = e0 + r;
        int ec = e < E ? e : (E - 1);
        const float* hi = node + (long)src[ec] * H + p * 32;
        const float* hj = node + (long)dst[ec] * H + p * 32;
        unsigned short* row = sEI + r * 520;
#pragma unroll
        for (int b = 0; b < 8; b++) {
            float4 a = ((const float4*)hi)[b];
            float4 c = ((const float4*)hj)[b];
            int c0 = p * 32 + b * 4;
            ushort4 wa, wc, wd, wp;
            wa.x = f2bf(a.x); wa.y = f2bf(a.y); wa.z = f2bf(a.z); wa.w = f2bf(a.w);
            wc.x = f2bf(c.x); wc.y = f2bf(c.y); wc.z = f2bf(c.z); wc.w = f2bf(c.w);
            wd.x = f2bf(fabsf(a.x - c.x)); wd.y = f2bf(fabsf(a.y - c.y));
            wd.z = f2bf(fabsf(a.z - c.z)); wd.w = f2bf(fabsf(a.w - c.w));
            wp.x = f2bf(a.x * c.x); wp.y = f2bf(a.y * c.y);
            wp.z = f2bf(a.z * c.z); wp.w = f2bf(a.w * c.w);
            *(ushort4*)(row + c0)       = wa;
            *(ushort4*)(row + 128 + c0) = wc;
            *(ushort4*)(row + 256 + c0) = wd;
            *(ushort4*)(row + 384 + c0) = wp;
        }
        sW3[(t & 1) * 128 + (t >> 1)] = W3[t];   // de-interleave [k][c] -> [c][k]
    }

    // ---------------- Layer-1 B prologue (independent of LDS; hides under build) --
    bf16x8 bbuf[8][4];
#pragma unroll
    for (int p = 0; p < 4; p++)
#pragma unroll
        for (int nt = 0; nt < 4; nt++)
            bbuf[p][nt] = *(const bf16x8*)(w1p[nt] + p * 32);

    f32x4 acc[4][4];
#pragma unroll
    for (int mt = 0; mt < 4; mt++)
#pragma unroll
        for (int nt = 0; nt < 4; nt++)
            acc[mt][nt] = (f32x4){0.f, 0.f, 0.f, 0.f};

    const unsigned short* sA[4];
#pragma unroll
    for (int mt = 0; mt < 4; mt++) sA[mt] = sEI + (mt * 16 + lrow) * 520 + quad * 8;

    __syncthreads();               // EI tile visible

    // ---------------- Phase B: layer 1  (M=64, N=256, K=512), pipelined ---------
    bf16x8 abuf[2][4];
#pragma unroll
    for (int mt = 0; mt < 4; mt++) abuf[0][mt] = *(const bf16x8*)(sA[mt]);

#pragma unroll
    for (int ks = 0; ks < 16; ks++) {
        const int cur = ks & 1;
        if (ks < 15) {
#pragma unroll
            for (int mt = 0; mt < 4; mt++)
                abuf[cur ^ 1][mt] = *(const bf16x8*)(sA[mt] + (ks + 1) * 32);
        }
        if (ks < 12) {
#pragma unroll
            for (int nt = 0; nt < 4; nt++)
                bbuf[(ks + 4) & 7][nt] = *(const bf16x8*)(w1p[nt] + (ks + 4) * 32);
        }
#pragma unroll
        for (int mt = 0; mt < 4; mt++)
#pragma unroll
            for (int nt = 0; nt < 4; nt++)
                acc[mt][nt] = __builtin_amdgcn_mfma_f32_16x16x32_bf16(
                    abuf[cur][mt], bbuf[ks & 7][nt], acc[mt][nt], 0, 0, 0);
    }

    // ---------------- Layer-2 B prologue (hides under epilogue C) ----------------
    bf16x8 b2buf[8][2];
#pragma unroll
    for (int p = 0; p < 4; p++)
#pragma unroll
        for (int nt = 0; nt < 2; nt++)
            b2buf[p][nt] = *(const bf16x8*)(w2p[nt] + p * 32);

    // ---------------- Phase C: relu+bias -> x1 bf16 in LDS (overlay EI) ---------
    float b1v[4];
#pragma unroll
    for (int nt = 0; nt < 4; nt++) b1v[nt] = b1[nb + nt * 16 + lrow];

    __syncthreads();               // all waves done reading sEI
    unsigned short* sx1 = sEI;     // [64][264]
#pragma unroll
    for (int mt = 0; mt < 4; mt++)
#pragma unroll
        for (int nt = 0; nt < 4; nt++)
#pragma unroll
            for (int i = 0; i < 4; i++) {
                int row = mt * 16 + quad * 4 + i;    // C/D: row = quad*4 + reg
                int col = nb + nt * 16 + lrow;       //      col = lane&15
                float v = acc[mt][nt][i] + b1v[nt];
                v = v > 0.f ? v : 0.f;
                sx1[row * 264 + col] = f2bf(v);
            }
    __syncthreads();               // x1 complete

    // ---------------- Phase D: layer 2  (M=64, N=128, K=256), pipelined ---------
    f32x4 acc2[4][2];
#pragma unroll
    for (int mt = 0; mt < 4; mt++)
#pragma unroll
        for (int nt = 0; nt < 2; nt++)
            acc2[mt][nt] = (f32x4){0.f, 0.f, 0.f, 0.f};

    const unsigned short* sA2[4];
#pragma unroll
    for (int mt = 0; mt < 4; mt++) sA2[mt] = sx1 + (mt * 16 + lrow) * 264 + quad * 8;

    bf16x8 a2buf[2][4];
#pragma unroll
    for (int mt = 0; mt < 4; mt++) a2buf[0][mt] = *(const bf16x8*)(sA2[mt]);

#pragma unroll
    for (int ks = 0; ks < 8; ks++) {
        const int cur = ks & 1;
        if (ks < 7) {
#pragma unroll
            for (int mt = 0; mt < 4; mt++)
                a2buf[cur ^ 1][mt] = *(const bf16x8*)(sA2[mt] + (ks + 1) * 32);
        }
        if (ks < 4) {
#pragma unroll
            for (int nt = 0; nt < 2; nt++)
                b2buf[(ks + 4) & 7][nt] = *(const bf16x8*)(w2p[nt] + (ks + 4) * 32);
        }
#pragma unroll
        for (int mt = 0; mt < 4; mt++)
#pragma unroll
            for (int nt = 0; nt < 2; nt++)
                acc2[mt][nt] = __builtin_amdgcn_mfma_f32_16x16x32_bf16(
                    a2buf[cur][mt], b2buf[ks & 7][nt], acc2[mt][nt], 0, 0, 0);
    }

    // ---------------- Phase E: relu+bias -> x2 bf16 in LDS -----------------------
    unsigned short* sx2 = sEI + 64 * 264;   // [64][136], disjoint from x1
    float b2v[2];
#pragma unroll
    for (int nt = 0; nt < 2; nt++) b2v[nt] = b2[nb2 + nt * 16 + lrow];
#pragma unroll
    for (int mt = 0; mt < 4; mt++)
#pragma unroll
        for (int nt = 0; nt < 2; nt++)
#pragma unroll
            for (int i = 0; i < 4; i++) {
                int row = mt * 16 + quad * 4 + i;
                int col = nb2 + nt * 16 + lrow;
                float v = acc2[mt][nt][i] + b2v[nt];
                v = v > 0.f ? v : 0.f;
                sx2[row * 136 + col] = f2bf(v);
            }
    __syncthreads();

    // ---------------- Phase F: layer 3 (N=2), all threads, half-dots -------------
    {
        int r = t >> 2;            // edge row 0..63
        int c = t & 1;             // class
        int h = (t >> 1) & 1;      // K-half
        const unsigned short* xr = sx2 + r * 136 + h * 64;
        const float* w3c = sW3 + c * 128 + h * 64;
        float s = 0.f;
#pragma unroll
        for (int j = 0; j < 8; j++) {
            uint4 v = *(const uint4*)(xr + j * 8);
            const float* w = w3c + j * 8;
            s += bflo(v.x) * w[0] + bfhi(v.x) * w[1]
               + bflo(v.y) * w[2] + bfhi(v.y) * w[3]
               + bflo(v.z) * w[4] + bfhi(v.z) * w[5]
               + bflo(v.w) * w[6] + bfhi(v.w) * w[7];
        }
        s += __shfl_xor(s, 2);     // combine K-halves (partner t^2, same wave)
        int e = e0 + r;
        if (h == 0 && e < E) out[e * 2 + c] = s + b3[c];
    }
}

extern "C" void kernel_launch(void* const* d_in, const int* in_sizes, int n_in,
                              void* d_out, int out_size, void* d_ws, size_t ws_size,
                              hipStream_t stream) {
    const float* node = (const float*)d_in[0];
    const int* src    = (const int*)d_in[1];
    const int* dst    = (const int*)d_in[2];
    const float* W1   = (const float*)d_in[3];
    const float* b1   = (const float*)d_in[4];
    const float* W2   = (const float*)d_in[5];
    const float* b2   = (const float*)d_in[6];
    const float* W3   = (const float*)d_in[7];
    const float* b3   = (const float*)d_in[8];
    float* out = (float*)d_out;
    const int E = in_sizes[1];

    unsigned short* W1T = (unsigned short*)d_ws;       // [256][512] bf16
    unsigned short* W2T = W1T + 512 * 256;             // [128][256] bf16

    hipLaunchKernelGGL(prep_w1, dim3(512), dim3(256), 0, stream, W1, W1T);
    hipLaunchKernelGGL(prep_w2, dim3(128), dim3(256), 0, stream, W2, W2T);
    const int nblk = (E + 63) / 64;
    hipLaunchKernelGGL(fused_mlp, dim3(nblk), dim3(256), 0, stream,
                       node, src, dst, W1T, b1, W2T, b2, W3, b3, out, E);
}